// Round 7
// baseline (1372.555 us; speedup 1.0000x reference)
//
#include <hip/hip_runtime.h>
#include <hip/hip_bf16.h>
#include <math.h>

#define N_NODES 50000
#define N_EDGES 800000
#define EMB 128
#define LH 256
#define NSENT 2048
#define MAXLEN 32
#define SCAN_NB 196   // ceil(50000/256)

typedef __attribute__((ext_vector_type(8))) short short8;
typedef __attribute__((ext_vector_type(4))) float f32x4;

__device__ __forceinline__ unsigned short f2bf_u(float f) {
    __hip_bfloat16 h = __float2bfloat16(f);
    return *reinterpret_cast<unsigned short*>(&h);
}
__device__ __forceinline__ float bfu2f(unsigned short u) {
    unsigned int x = ((unsigned int)u) << 16;
    return __uint_as_float(x);
}

// ---------------- CSR build ----------------

__global__ void k_hist(const int* __restrict__ dst, int* __restrict__ cnt) {
    int i = blockIdx.x * 256 + threadIdx.x;
    if (i < N_EDGES) atomicAdd(&cnt[dst[i]], 1);
}

__global__ void k_scan_blk(const int* __restrict__ cnt, int* __restrict__ row_ptr,
                           int* __restrict__ blk) {
    int b = blockIdx.x, t = threadIdx.x;
    int i = b * 256 + t;
    int lane = t & 63, wid = t >> 6;
    int v = (i < N_NODES) ? cnt[i] : 0;
    int x = v;
    #pragma unroll
    for (int off = 1; off < 64; off <<= 1) {
        int y = __shfl_up(x, off);
        if (lane >= off) x += y;
    }
    __shared__ int ws[4];
    if (lane == 63) ws[wid] = x;
    __syncthreads();
    if (t == 0) {
        int s = 0;
        #pragma unroll
        for (int j = 0; j < 4; j++) { int tmp = ws[j]; ws[j] = s; s += tmp; }
        blk[b] = s;
    }
    __syncthreads();
    if (i < N_NODES) row_ptr[i] = ws[wid] + x - v;
}

__global__ void k_scan_tot(int* __restrict__ blk) {
    int t = threadIdx.x;
    int lane = t & 63, wid = t >> 6;
    int v = (t < SCAN_NB) ? blk[t] : 0;
    int x = v;
    #pragma unroll
    for (int off = 1; off < 64; off <<= 1) {
        int y = __shfl_up(x, off);
        if (lane >= off) x += y;
    }
    __shared__ int ws[4];
    if (lane == 63) ws[wid] = x;
    __syncthreads();
    if (t == 0) {
        int s = 0;
        #pragma unroll
        for (int j = 0; j < 4; j++) { int tmp = ws[j]; ws[j] = s; s += tmp; }
    }
    __syncthreads();
    if (t < SCAN_NB) blk[t] = ws[wid] + x - v;
}

__global__ void k_scan_add(int* __restrict__ row_ptr, const int* __restrict__ blk) {
    int i = blockIdx.x * 256 + threadIdx.x;
    if (i < N_NODES) row_ptr[i] += blk[i >> 8];
    if (i == 0) row_ptr[N_NODES] = N_EDGES;
}

__global__ void k_scatter(const int* __restrict__ src, const int* __restrict__ dst,
                          const int* __restrict__ row_ptr, int* __restrict__ cnt,
                          int* __restrict__ edge_src) {
    int i = blockIdx.x * 256 + threadIdx.x;
    if (i < N_EDGES) {
        int d = dst[i];
        int pos = row_ptr[d] + atomicAdd(&cnt[d], 1);
        edge_src[pos] = src[i];
    }
}

// ---------------- fp32 -> bf16 convert (inputs) ----------------

__global__ void k_tobf16(const float* __restrict__ x, unsigned short* __restrict__ y) {
    int i = blockIdx.x * 256 + threadIdx.x;
    float4 v = ((const float4*)x)[i];
    ushort4 u;
    u.x = f2bf_u(v.x); u.y = f2bf_u(v.y); u.z = f2bf_u(v.z); u.w = f2bf_u(v.w);
    ((ushort4*)y)[i] = u;
}

// ---------------- aggregation: wave per node, 4 edge-slots x 16B/lane ----------------

__global__ void k_aggregate_bf(const unsigned short* __restrict__ feat,
                               const int* __restrict__ row_ptr,
                               const int* __restrict__ edge_src,
                               unsigned short* __restrict__ outb) {
    int w = (blockIdx.x * 256 + threadIdx.x) >> 6;
    int lane = threadIdx.x & 63;
    if (w >= N_NODES) return;
    int slot = lane >> 4, li = lane & 15;
    int beg = row_ptr[w], end = row_ptr[w + 1];
    float acc[8] = {};
    #pragma unroll 1
    for (int e = beg; e < end; e += 4) {
        int eidx = e + slot;
        if (eidx < end) {
            int s = edge_src[eidx];
            short8 v = *(const short8*)((const short*)feat + (size_t)s * EMB + li * 8);
            #pragma unroll
            for (int j = 0; j < 8; j++) acc[j] += bfu2f((unsigned short)v[j]);
        }
    }
    #pragma unroll
    for (int j = 0; j < 8; j++) {
        float t = acc[j];
        t += __shfl_xor(t, 16);
        t += __shfl_xor(t, 32);
        acc[j] = t;
    }
    if (slot == 0) {
        short8 o;
        #pragma unroll
        for (int j = 0; j < 8; j++) o[j] = (short)f2bf_u(acc[j]);
        *(short8*)((short*)outb + (size_t)w * EMB + li * 8) = o;
    }
}

// ---------------- GCN linear via MFMA ----------------

__global__ void __launch_bounds__(256)
k_gcn_mfma(const unsigned short* __restrict__ Ab,   // [M][128] bf16
           const unsigned short* __restrict__ Wb,   // [128][128] bf16
           const float* __restrict__ bias,
           unsigned short* __restrict__ outb,
           int M, int do_tanh) {
    int tid = threadIdx.x;
    int w = tid >> 6, lane = tid & 63;
    int l16 = lane & 15, quad = lane >> 4;
    int rbase = blockIdx.x * 64 + w * 16;
    int arow = rbase + l16;
    if (arow >= M) arow = M - 1;
    const short* Ap = (const short*)Ab + (size_t)arow * 128 + quad * 8;
    const short* Wp = (const short*)Wb;
    f32x4 acc[8] = {};
    #pragma unroll
    for (int ks = 0; ks < 4; ks++) {
        short8 a = *(const short8*)(Ap + ks * 32);
        #pragma unroll
        for (int ct = 0; ct < 8; ct++) {
            short8 b = *(const short8*)(Wp + (size_t)(ct * 16 + l16) * 128 + ks * 32 + quad * 8);
            acc[ct] = __builtin_amdgcn_mfma_f32_16x16x32_bf16(a, b, acc[ct], 0, 0, 0);
        }
    }
    #pragma unroll
    for (int ct = 0; ct < 8; ct++) {
        float bcol = bias[ct * 16 + l16];
        #pragma unroll
        for (int r = 0; r < 4; r++) {
            int row = rbase + quad * 4 + r;
            if (row < M) {
                float v = acc[ct][r] + bcol;
                if (do_tanh) v = tanhf(v);
                outb[(size_t)row * 128 + ct * 16 + l16] = f2bf_u(v);
            }
        }
    }
}

// ---------------- prep: Wpk (fragment-linear packed LSTM weights), bsum, W1b, W2b ----------------
// Wpk: fragment (ct,ks) at ((ct*12+ks)<<9) shorts; element lane*8+jj =
//   W[ct*16 + (lane&15)][ks*32 + (lane>>4)*8 + jj]  -> 1KB coalesced per wave-load.

__global__ void k_prep(const float* __restrict__ Wi, const float* __restrict__ Wh,
                       const float* __restrict__ bi, const float* __restrict__ bh,
                       const float* __restrict__ W1, const float* __restrict__ W2,
                       unsigned short* __restrict__ Wpk, float* __restrict__ bsum,
                       unsigned short* __restrict__ W1b, unsigned short* __restrict__ W2b) {
    int idx = blockIdx.x * 256 + threadIdx.x;
    if (idx < 1024 * 384) {
        int R = idx / 384, k = idx - R * 384;
        float v = (k < 128) ? Wi[R * 128 + k] : Wh[R * 256 + (k - 128)];
        int ct = R >> 4, cin = R & 15;
        int ks = k >> 5, kk = k & 31;
        int q = kk >> 3, jj = kk & 7;
        Wpk[((ct * 12 + ks) << 9) + (q * 16 + cin) * 8 + jj] = f2bf_u(v);
    } else if (idx < 1024 * 384 + 1024) {
        int r = idx - 1024 * 384;
        bsum[r] = bi[r] + bh[r];
    } else if (idx < 1024 * 384 + 1024 + 16384) {
        int r = idx - (1024 * 384 + 1024);
        W1b[r] = f2bf_u(W1[r]);
    } else if (idx < 1024 * 384 + 1024 + 32768) {
        int r = idx - (1024 * 384 + 1024 + 16384);
        W2b[r] = f2bf_u(W2[r]);
    }
}

// ---------------- LSTM: 64 self-contained blocks x 512 threads (8 waves) ----------------
// R4's proven no-spill envelope (512 thr, launch_bounds(512,2), 8 ct/wave) + macro-expanded
// ping-pong weight prefetch with LITERAL ks indices (R5/R6 lesson: a rolled loop with
// runtime bb[cur]/bb[nxt] indices demotes bb+acc to scratch -> 750 MB deterministic HBM
// traffic). bbA/bbB are named arrays, every index compile-time. h in LDS, XOR-swizzled
// (verified in R6); c in registers; weights stream from XCD L2 (~768 KB/step/CU floor).

#define LOADB(BUF, KS) { \
    _Pragma("unroll") \
    for (int c8 = 0; c8 < 8; c8++) { \
        int ct = (c8 >> 1) * 16 + w * 2 + (c8 & 1); \
        BUF[c8] = *(const short8*)(Wp + ((ct * 12 + (KS)) << 9) + lane * 8); \
    } }

#define DOMFMA(BUF, KS) { \
    short8 a0, a1; \
    if ((KS) < 4) { \
        a0 = *(const short8*)(Ax0 + (KS) * 32); \
        a1 = *(const short8*)(Ax1 + (KS) * 32); \
    } else { \
        int go = (((KS) - 4) * 4 + quad) * 8; \
        a0 = *(const short8*)(hin + l16 * 256 + (go ^ swz)); \
        a1 = *(const short8*)(hin + (16 + l16) * 256 + (go ^ swz)); \
    } \
    _Pragma("unroll") \
    for (int c8 = 0; c8 < 8; c8++) { \
        acc0[c8] = __builtin_amdgcn_mfma_f32_16x16x32_bf16(a0, BUF[c8], acc0[c8], 0, 0, 0); \
        acc1[c8] = __builtin_amdgcn_mfma_f32_16x16x32_bf16(a1, BUF[c8], acc1[c8], 0, 0, 0); \
    } }

__global__ void __launch_bounds__(512, 2)
k_lstm_block(const unsigned short* __restrict__ hn_bf,   // [N_NODES][128] bf16
             const unsigned short* __restrict__ Wpk,     // packed, see k_prep
             const float* __restrict__ bsum,             // [1024]
             const int* __restrict__ sidx,               // [NSENT][MAXLEN]
             const int* __restrict__ lengths,            // [NSENT]
             float* __restrict__ h_last) {               // [NSENT][256] fp32
    __shared__ unsigned short hsh[2][32 * 256];          // 32 KB
    __shared__ int nid_sh[32 * 33];                      // [m][t], pitch 33
    __shared__ int len_sh[32];
    int tid = threadIdx.x;
    int w = tid >> 6, lane = tid & 63;                   // w in [0,8)
    int l16 = lane & 15, quad = lane >> 4;
    int s0 = blockIdx.x * 32;

    for (int i = tid; i < 32 * 32; i += 512)
        nid_sh[(i >> 5) * 33 + (i & 31)] = sidx[(size_t)(s0 + (i >> 5)) * MAXLEN + (i & 31)];
    if (tid < 32) len_sh[tid] = lengths[s0 + tid];
    for (int i = tid; i < 32 * 256; i += 512) hsh[0][i] = 0;   // h_{-1} = 0
    __syncthreads();

    const short* hnp = (const short*)hn_bf;
    const short* Wp = (const short*)Wpk;

    float bs[4][2];
    #pragma unroll
    for (int g = 0; g < 4; g++)
        #pragma unroll
        for (int us = 0; us < 2; us++)
            bs[g][us] = bsum[g * 256 + w * 32 + us * 16 + l16];

    float c_reg[2][2][4] = {};   // [mt][us][r]
    int swz = (l16 & 7) * 8;     // XOR term (shorts) for h LDS chunk swizzle

    #pragma unroll 1
    for (int t = 0; t < MAXLEN; t++) {
        const short* hin = (const short*)hsh[t & 1];
        unsigned short* hout = hsh[(t & 1) ^ 1];

        int nid0 = nid_sh[l16 * 33 + t];
        int nid1 = nid_sh[(16 + l16) * 33 + t];
        const short* Ax0 = hnp + (size_t)nid0 * 128 + quad * 8;
        const short* Ax1 = hnp + (size_t)nid1 * 128 + quad * 8;

        f32x4 acc0[8] = {};   // m-tile 0, [g*2+us]
        f32x4 acc1[8] = {};   // m-tile 1
        short8 bbA[8], bbB[8];

        // macro-expanded pipeline: LOADB one stage ahead of its DOMFMA, all ks literal
        LOADB(bbA, 0)
        LOADB(bbB, 1)
        DOMFMA(bbA, 0)
        LOADB(bbA, 2)
        DOMFMA(bbB, 1)
        LOADB(bbB, 3)
        DOMFMA(bbA, 2)
        LOADB(bbA, 4)
        DOMFMA(bbB, 3)
        LOADB(bbB, 5)
        DOMFMA(bbA, 4)
        LOADB(bbA, 6)
        DOMFMA(bbB, 5)
        LOADB(bbB, 7)
        DOMFMA(bbA, 6)
        LOADB(bbA, 8)
        DOMFMA(bbB, 7)
        LOADB(bbB, 9)
        DOMFMA(bbA, 8)
        LOADB(bbA, 10)
        DOMFMA(bbB, 9)
        LOADB(bbB, 11)
        DOMFMA(bbA, 10)
        DOMFMA(bbB, 11)

        // epilogue: per-lane pointwise update; c in registers; h -> LDS (swizzled)
        #pragma unroll
        for (int mt = 0; mt < 2; mt++)
            #pragma unroll
            for (int us = 0; us < 2; us++)
                #pragma unroll
                for (int r = 0; r < 4; r++) {
                    int m = mt * 16 + quad * 4 + r;
                    int u = w * 32 + us * 16 + l16;
                    float gi  = (mt ? acc1[0 * 2 + us][r] : acc0[0 * 2 + us][r]) + bs[0][us];
                    float gf  = (mt ? acc1[1 * 2 + us][r] : acc0[1 * 2 + us][r]) + bs[1][us];
                    float gg  = (mt ? acc1[2 * 2 + us][r] : acc0[2 * 2 + us][r]) + bs[2][us];
                    float go_ = (mt ? acc1[3 * 2 + us][r] : acc0[3 * 2 + us][r]) + bs[3][us];
                    float i_ = 1.f / (1.f + expf(-gi));
                    float f_ = 1.f / (1.f + expf(-gf));
                    float g_ = tanhf(gg);
                    float o_ = 1.f / (1.f + expf(-go_));
                    float c = f_ * c_reg[mt][us][r] + i_ * g_;
                    c_reg[mt][us][r] = c;
                    float h = o_ * tanhf(c);
                    hout[m * 256 + ((((u >> 3) ^ (m & 7)) << 3) | (u & 7))] = f2bf_u(h);
                    if (len_sh[m] - 1 == t) h_last[(size_t)(s0 + m) * 256 + u] = h;
                }
        __syncthreads();
    }
}

// ---------------- classifier ----------------

__global__ void k_classifier(const float* __restrict__ h_last,
                             const float* __restrict__ Wc1, const float* __restrict__ bc1,
                             const float* __restrict__ Wc2, const float* __restrict__ bc2,
                             float* __restrict__ out) {
    int lane = threadIdx.x & 63;
    int wslot = threadIdx.x >> 6;
    int s = blockIdx.x * 4 + wslot;
    __shared__ float e_sh[4][256];
    const float* hr = h_last + (size_t)s * 256;
    #pragma unroll
    for (int i = 0; i < 4; i++) {
        float v = hr[lane + 64 * i];
        e_sh[wslot][lane + 64 * i] = fmaxf(v, 0.f);
    }
    __syncthreads();
    float zpart = 0.f;
    #pragma unroll
    for (int jj = 0; jj < 2; jj++) {
        int j = lane + 64 * jj;
        float a = bc1[j];
        const float4* wr = (const float4*)(Wc1 + (size_t)j * 256);
        #pragma unroll 8
        for (int k4 = 0; k4 < 64; k4++) {
            float4 wv = wr[k4];
            float4 e = *(const float4*)&e_sh[wslot][k4 * 4];
            a += wv.x * e.x + wv.y * e.y + wv.z * e.z + wv.w * e.w;
        }
        a = fmaxf(a, 0.f);
        zpart += a * Wc2[j];
    }
    #pragma unroll
    for (int off = 32; off > 0; off >>= 1) zpart += __shfl_down(zpart, off);
    if (lane == 0) out[s] = zpart + bc2[0];
}

// ---------------- launcher ----------------

extern "C" void kernel_launch(void* const* d_in, const int* in_sizes, int n_in,
                              void* d_out, int out_size, void* d_ws, size_t ws_size,
                              hipStream_t stream) {
    const float* inputs = (const float*)d_in[0];
    const float* W1  = (const float*)d_in[1];
    const float* b1  = (const float*)d_in[2];
    const float* W2  = (const float*)d_in[3];
    const float* b2  = (const float*)d_in[4];
    const float* Wi  = (const float*)d_in[5];
    const float* Wh  = (const float*)d_in[6];
    const float* bi  = (const float*)d_in[7];
    const float* bh  = (const float*)d_in[8];
    const float* Wc1 = (const float*)d_in[9];
    const float* bc1 = (const float*)d_in[10];
    const float* Wc2 = (const float*)d_in[11];
    const float* bc2 = (const float*)d_in[12];
    const int* src      = (const int*)d_in[13];
    const int* dst      = (const int*)d_in[14];
    const int* sidx     = (const int*)d_in[15];
    const int* lengths  = (const int*)d_in[16];
    float* out = (float*)d_out;

    char* ws = (char*)d_ws;
    size_t off = 0;
    auto alloc = [&](size_t bytes) -> void* {
        void* p = ws + off;
        off = (off + bytes + 255) & ~(size_t)255;
        return p;
    };
    unsigned short* in_bf  = (unsigned short*)alloc(2 * (size_t)N_NODES * EMB);
    unsigned short* agg_bf = (unsigned short*)alloc(2 * (size_t)N_NODES * EMB);
    unsigned short* h_bf   = (unsigned short*)alloc(2 * (size_t)N_NODES * EMB);
    unsigned short* hn_bf  = (unsigned short*)alloc(2 * (size_t)N_NODES * EMB);
    int*   row_ptr  = (int*)alloc(sizeof(int) * (N_NODES + 1));
    int*   cnt      = (int*)alloc(sizeof(int) * N_NODES);
    int*   blk      = (int*)alloc(sizeof(int) * SCAN_NB);
    int*   edge_src = (int*)alloc(sizeof(int) * N_EDGES);
    unsigned short* Wpk  = (unsigned short*)alloc(2 * 1024 * 384);
    unsigned short* W1b  = (unsigned short*)alloc(2 * 128 * 128);
    unsigned short* W2b  = (unsigned short*)alloc(2 * 128 * 128);
    float* bsum     = (float*)alloc(sizeof(float) * 1024);
    float* hlast    = (float*)alloc(sizeof(float) * NSENT * LH);

    // weight prep (independent of everything else)
    k_prep<<<(1024 * 384 + 1024 + 32768 + 255) / 256, 256, 0, stream>>>(
        Wi, Wh, bi, bh, W1, W2, Wpk, bsum, W1b, W2b);

    // CSR build
    hipMemsetAsync(cnt, 0, sizeof(int) * N_NODES, stream);
    k_hist<<<(N_EDGES + 255) / 256, 256, 0, stream>>>(dst, cnt);
    k_scan_blk<<<SCAN_NB, 256, 0, stream>>>(cnt, row_ptr, blk);
    k_scan_tot<<<1, 256, 0, stream>>>(blk);
    k_scan_add<<<SCAN_NB, 256, 0, stream>>>(row_ptr, blk);
    hipMemsetAsync(cnt, 0, sizeof(int) * N_NODES, stream);
    k_scatter<<<(N_EDGES + 255) / 256, 256, 0, stream>>>(src, dst, row_ptr, cnt, edge_src);

    // GCN (bf16 path)
    k_tobf16<<<(N_NODES * EMB / 4 + 255) / 256, 256, 0, stream>>>(inputs, in_bf);
    k_aggregate_bf<<<(N_NODES * 64) / 256, 256, 0, stream>>>(in_bf, row_ptr, edge_src, agg_bf);
    k_gcn_mfma<<<(N_NODES + 63) / 64, 256, 0, stream>>>(agg_bf, W1b, b1, h_bf, N_NODES, 1);
    k_aggregate_bf<<<(N_NODES * 64) / 256, 256, 0, stream>>>(h_bf, row_ptr, edge_src, agg_bf);
    k_gcn_mfma<<<(N_NODES + 63) / 64, 256, 0, stream>>>(agg_bf, W2b, b2, hn_bf, N_NODES, 0);

    // LSTM: 64 self-contained blocks x 512 threads, no inter-block sync
    k_lstm_block<<<64, 512, 0, stream>>>(hn_bf, Wpk, bsum, sidx, lengths, hlast);

    // classifier
    k_classifier<<<NSENT / 4, 256, 0, stream>>>(hlast, Wc1, bc1, Wc2, bc2, out);
}

// Round 8
// 1269.848 us; speedup vs baseline: 1.0809x; 1.0809x over previous
//
#include <hip/hip_runtime.h>
#include <hip/hip_bf16.h>
#include <math.h>

#define N_NODES 50000
#define N_EDGES 800000
#define EMB 128
#define LH 256
#define NSENT 2048
#define MAXLEN 32
#define SCAN_NB 196   // ceil(50000/256)

typedef __attribute__((ext_vector_type(8))) short short8;
typedef __attribute__((ext_vector_type(4))) float f32x4;

__device__ __forceinline__ unsigned short f2bf_u(float f) {
    __hip_bfloat16 h = __float2bfloat16(f);
    return *reinterpret_cast<unsigned short*>(&h);
}
__device__ __forceinline__ float bfu2f(unsigned short u) {
    unsigned int x = ((unsigned int)u) << 16;
    return __uint_as_float(x);
}

// ---------------- CSR build ----------------

__global__ void k_hist(const int* __restrict__ dst, int* __restrict__ cnt) {
    int i = blockIdx.x * 256 + threadIdx.x;
    if (i < N_EDGES) atomicAdd(&cnt[dst[i]], 1);
}

__global__ void k_scan_blk(const int* __restrict__ cnt, int* __restrict__ row_ptr,
                           int* __restrict__ blk) {
    int b = blockIdx.x, t = threadIdx.x;
    int i = b * 256 + t;
    int lane = t & 63, wid = t >> 6;
    int v = (i < N_NODES) ? cnt[i] : 0;
    int x = v;
    #pragma unroll
    for (int off = 1; off < 64; off <<= 1) {
        int y = __shfl_up(x, off);
        if (lane >= off) x += y;
    }
    __shared__ int ws[4];
    if (lane == 63) ws[wid] = x;
    __syncthreads();
    if (t == 0) {
        int s = 0;
        #pragma unroll
        for (int j = 0; j < 4; j++) { int tmp = ws[j]; ws[j] = s; s += tmp; }
        blk[b] = s;
    }
    __syncthreads();
    if (i < N_NODES) row_ptr[i] = ws[wid] + x - v;
}

__global__ void k_scan_tot(int* __restrict__ blk) {
    int t = threadIdx.x;
    int lane = t & 63, wid = t >> 6;
    int v = (t < SCAN_NB) ? blk[t] : 0;
    int x = v;
    #pragma unroll
    for (int off = 1; off < 64; off <<= 1) {
        int y = __shfl_up(x, off);
        if (lane >= off) x += y;
    }
    __shared__ int ws[4];
    if (lane == 63) ws[wid] = x;
    __syncthreads();
    if (t == 0) {
        int s = 0;
        #pragma unroll
        for (int j = 0; j < 4; j++) { int tmp = ws[j]; ws[j] = s; s += tmp; }
    }
    __syncthreads();
    if (t < SCAN_NB) blk[t] = ws[wid] + x - v;
}

__global__ void k_scan_add(int* __restrict__ row_ptr, const int* __restrict__ blk) {
    int i = blockIdx.x * 256 + threadIdx.x;
    if (i < N_NODES) row_ptr[i] += blk[i >> 8];
    if (i == 0) row_ptr[N_NODES] = N_EDGES;
}

__global__ void k_scatter(const int* __restrict__ src, const int* __restrict__ dst,
                          const int* __restrict__ row_ptr, int* __restrict__ cnt,
                          int* __restrict__ edge_src) {
    int i = blockIdx.x * 256 + threadIdx.x;
    if (i < N_EDGES) {
        int d = dst[i];
        int pos = row_ptr[d] + atomicAdd(&cnt[d], 1);
        edge_src[pos] = src[i];
    }
}

// ---------------- fp32 -> bf16 convert (inputs) ----------------

__global__ void k_tobf16(const float* __restrict__ x, unsigned short* __restrict__ y) {
    int i = blockIdx.x * 256 + threadIdx.x;
    float4 v = ((const float4*)x)[i];
    ushort4 u;
    u.x = f2bf_u(v.x); u.y = f2bf_u(v.y); u.z = f2bf_u(v.z); u.w = f2bf_u(v.w);
    ((ushort4*)y)[i] = u;
}

// ---------------- aggregation: wave per node, 4 edge-slots x 16B/lane ----------------

__global__ void k_aggregate_bf(const unsigned short* __restrict__ feat,
                               const int* __restrict__ row_ptr,
                               const int* __restrict__ edge_src,
                               unsigned short* __restrict__ outb) {
    int w = (blockIdx.x * 256 + threadIdx.x) >> 6;
    int lane = threadIdx.x & 63;
    if (w >= N_NODES) return;
    int slot = lane >> 4, li = lane & 15;
    int beg = row_ptr[w], end = row_ptr[w + 1];
    float acc[8] = {};
    #pragma unroll 1
    for (int e = beg; e < end; e += 4) {
        int eidx = e + slot;
        if (eidx < end) {
            int s = edge_src[eidx];
            short8 v = *(const short8*)((const short*)feat + (size_t)s * EMB + li * 8);
            #pragma unroll
            for (int j = 0; j < 8; j++) acc[j] += bfu2f((unsigned short)v[j]);
        }
    }
    #pragma unroll
    for (int j = 0; j < 8; j++) {
        float t = acc[j];
        t += __shfl_xor(t, 16);
        t += __shfl_xor(t, 32);
        acc[j] = t;
    }
    if (slot == 0) {
        short8 o;
        #pragma unroll
        for (int j = 0; j < 8; j++) o[j] = (short)f2bf_u(acc[j]);
        *(short8*)((short*)outb + (size_t)w * EMB + li * 8) = o;
    }
}

// ---------------- GCN linear via MFMA ----------------

__global__ void __launch_bounds__(256)
k_gcn_mfma(const unsigned short* __restrict__ Ab,   // [M][128] bf16
           const unsigned short* __restrict__ Wb,   // [128][128] bf16
           const float* __restrict__ bias,
           unsigned short* __restrict__ outb,
           int M, int do_tanh) {
    int tid = threadIdx.x;
    int w = tid >> 6, lane = tid & 63;
    int l16 = lane & 15, quad = lane >> 4;
    int rbase = blockIdx.x * 64 + w * 16;
    int arow = rbase + l16;
    if (arow >= M) arow = M - 1;
    const short* Ap = (const short*)Ab + (size_t)arow * 128 + quad * 8;
    const short* Wp = (const short*)Wb;
    f32x4 acc[8] = {};
    #pragma unroll
    for (int ks = 0; ks < 4; ks++) {
        short8 a = *(const short8*)(Ap + ks * 32);
        #pragma unroll
        for (int ct = 0; ct < 8; ct++) {
            short8 b = *(const short8*)(Wp + (size_t)(ct * 16 + l16) * 128 + ks * 32 + quad * 8);
            acc[ct] = __builtin_amdgcn_mfma_f32_16x16x32_bf16(a, b, acc[ct], 0, 0, 0);
        }
    }
    #pragma unroll
    for (int ct = 0; ct < 8; ct++) {
        float bcol = bias[ct * 16 + l16];
        #pragma unroll
        for (int r = 0; r < 4; r++) {
            int row = rbase + quad * 4 + r;
            if (row < M) {
                float v = acc[ct][r] + bcol;
                if (do_tanh) v = tanhf(v);
                outb[(size_t)row * 128 + ct * 16 + l16] = f2bf_u(v);
            }
        }
    }
}

// ---------------- prep: Wpk (fragment-linear packed LSTM weights), bsum, W1b, W2b ----------------
// Wpk: fragment (ct,ks) at ((ct*12+ks)<<9) shorts; element lane*8+jj =
//   W[ct*16 + (lane&15)][ks*32 + (lane>>4)*8 + jj]  -> 1KB coalesced per wave-load.

__global__ void k_prep(const float* __restrict__ Wi, const float* __restrict__ Wh,
                       const float* __restrict__ bi, const float* __restrict__ bh,
                       const float* __restrict__ W1, const float* __restrict__ W2,
                       unsigned short* __restrict__ Wpk, float* __restrict__ bsum,
                       unsigned short* __restrict__ W1b, unsigned short* __restrict__ W2b) {
    int idx = blockIdx.x * 256 + threadIdx.x;
    if (idx < 1024 * 384) {
        int R = idx / 384, k = idx - R * 384;
        float v = (k < 128) ? Wi[R * 128 + k] : Wh[R * 256 + (k - 128)];
        int ct = R >> 4, cin = R & 15;
        int ks = k >> 5, kk = k & 31;
        int q = kk >> 3, jj = kk & 7;
        Wpk[((ct * 12 + ks) << 9) + (q * 16 + cin) * 8 + jj] = f2bf_u(v);
    } else if (idx < 1024 * 384 + 1024) {
        int r = idx - 1024 * 384;
        bsum[r] = bi[r] + bh[r];
    } else if (idx < 1024 * 384 + 1024 + 16384) {
        int r = idx - (1024 * 384 + 1024);
        W1b[r] = f2bf_u(W1[r]);
    } else if (idx < 1024 * 384 + 1024 + 32768) {
        int r = idx - (1024 * 384 + 1024 + 16384);
        W2b[r] = f2bf_u(W2[r]);
    }
}

// ---------------- LSTM: 64 self-contained blocks x 1024 threads (16 waves) ----------------
// Lessons combined: R6's register budget (4 ct/wave -> ~97 VGPR) + R7's codegen (macro-
// expanded ping-pong, every ks index a literal; rolled loops with runtime buffer indices
// demote arrays to scratch -> 700 MB HBM spill traffic). launch_bounds(1024,1): 1 block/CU,
// 16 waves = 4 waves/EU -> 128-VGPR cap, budget fits. Wave w owns units [w*16,w*16+16),
// all 4 gates (ct = g*16 + w). h in LDS double-buffer, XOR-swizzled (chunk ^ (m&7));
// c in registers; weights stream from XCD L2: 768 KB/step/CU / ~60 B/cyc ~= 5.3 us/step.

#define LOADB(BUF, KS) { \
    _Pragma("unroll") \
    for (int g = 0; g < 4; g++) { \
        int ct = g * 16 + w; \
        BUF[g] = *(const short8*)(Wp + ((ct * 12 + (KS)) << 9) + lane * 8); \
    } }

#define DOMFMA(BUF, KS) { \
    short8 a0, a1; \
    if ((KS) < 4) { \
        a0 = *(const short8*)(Ax0 + (KS) * 32); \
        a1 = *(const short8*)(Ax1 + (KS) * 32); \
    } else { \
        int go = (((KS) - 4) * 4 + quad) * 8; \
        a0 = *(const short8*)(hin + l16 * 256 + (go ^ swz)); \
        a1 = *(const short8*)(hin + (16 + l16) * 256 + (go ^ swz)); \
    } \
    _Pragma("unroll") \
    for (int g = 0; g < 4; g++) { \
        acc0[g] = __builtin_amdgcn_mfma_f32_16x16x32_bf16(a0, BUF[g], acc0[g], 0, 0, 0); \
        acc1[g] = __builtin_amdgcn_mfma_f32_16x16x32_bf16(a1, BUF[g], acc1[g], 0, 0, 0); \
    } }

__global__ void __launch_bounds__(1024, 1)
k_lstm_block(const unsigned short* __restrict__ hn_bf,   // [N_NODES][128] bf16
             const unsigned short* __restrict__ Wpk,     // packed, see k_prep
             const float* __restrict__ bsum,             // [1024]
             const int* __restrict__ sidx,               // [NSENT][MAXLEN]
             const int* __restrict__ lengths,            // [NSENT]
             float* __restrict__ h_last) {               // [NSENT][256] fp32
    __shared__ unsigned short hsh[2][32 * 256];          // 32 KB
    __shared__ int nid_sh[32 * 33];                      // [m][t], pitch 33
    __shared__ int len_sh[32];
    int tid = threadIdx.x;
    int w = tid >> 6, lane = tid & 63;                   // w in [0,16)
    int l16 = lane & 15, quad = lane >> 4;
    int s0 = blockIdx.x * 32;

    for (int i = tid; i < 32 * 32; i += 1024)
        nid_sh[(i >> 5) * 33 + (i & 31)] = sidx[(size_t)(s0 + (i >> 5)) * MAXLEN + (i & 31)];
    if (tid < 32) len_sh[tid] = lengths[s0 + tid];
    for (int i = tid; i < 32 * 256; i += 1024) hsh[0][i] = 0;   // h_{-1} = 0
    __syncthreads();

    const short* hnp = (const short*)hn_bf;
    const short* Wp = (const short*)Wpk;

    float bs[4];
    #pragma unroll
    for (int g = 0; g < 4; g++) bs[g] = bsum[g * 256 + w * 16 + l16];

    float c_reg[2][4] = {};   // [mt][r]
    int u = w * 16 + l16;
    int swz = (l16 & 7) * 8;  // XOR term (shorts) for h LDS chunk swizzle

    #pragma unroll 1
    for (int t = 0; t < MAXLEN; t++) {
        const short* hin = (const short*)hsh[t & 1];
        unsigned short* hout = hsh[(t & 1) ^ 1];

        int nid0 = nid_sh[l16 * 33 + t];
        int nid1 = nid_sh[(16 + l16) * 33 + t];
        const short* Ax0 = hnp + (size_t)nid0 * 128 + quad * 8;
        const short* Ax1 = hnp + (size_t)nid1 * 128 + quad * 8;

        f32x4 acc0[4] = {};   // m-tile 0 (m = quad*4+r), per gate
        f32x4 acc1[4] = {};   // m-tile 1 (m = 16+quad*4+r)
        short8 bbA[4], bbB[4];

        // macro-expanded pipeline: LOADB one stage ahead of its DOMFMA, all ks literal
        LOADB(bbA, 0)
        LOADB(bbB, 1)
        DOMFMA(bbA, 0)
        LOADB(bbA, 2)
        DOMFMA(bbB, 1)
        LOADB(bbB, 3)
        DOMFMA(bbA, 2)
        LOADB(bbA, 4)
        DOMFMA(bbB, 3)
        LOADB(bbB, 5)
        DOMFMA(bbA, 4)
        LOADB(bbA, 6)
        DOMFMA(bbB, 5)
        LOADB(bbB, 7)
        DOMFMA(bbA, 6)
        LOADB(bbA, 8)
        DOMFMA(bbB, 7)
        LOADB(bbB, 9)
        DOMFMA(bbA, 8)
        LOADB(bbA, 10)
        DOMFMA(bbB, 9)
        LOADB(bbB, 11)
        DOMFMA(bbA, 10)
        DOMFMA(bbB, 11)

        // epilogue: per-lane pointwise update; c in registers; h -> LDS (swizzled)
        #pragma unroll
        for (int mt = 0; mt < 2; mt++)
            #pragma unroll
            for (int r = 0; r < 4; r++) {
                int m = mt * 16 + quad * 4 + r;
                float gi  = (mt ? acc1[0][r] : acc0[0][r]) + bs[0];
                float gf  = (mt ? acc1[1][r] : acc0[1][r]) + bs[1];
                float gg  = (mt ? acc1[2][r] : acc0[2][r]) + bs[2];
                float go_ = (mt ? acc1[3][r] : acc0[3][r]) + bs[3];
                float i_ = 1.f / (1.f + expf(-gi));
                float f_ = 1.f / (1.f + expf(-gf));
                float g_ = tanhf(gg);
                float o_ = 1.f / (1.f + expf(-go_));
                float c = f_ * c_reg[mt][r] + i_ * g_;
                c_reg[mt][r] = c;
                float h = o_ * tanhf(c);
                hout[m * 256 + ((((u >> 3) ^ (m & 7)) << 3) | (u & 7))] = f2bf_u(h);
                if (len_sh[m] - 1 == t) h_last[(size_t)(s0 + m) * 256 + u] = h;
            }
        __syncthreads();
    }
}

// ---------------- classifier ----------------

__global__ void k_classifier(const float* __restrict__ h_last,
                             const float* __restrict__ Wc1, const float* __restrict__ bc1,
                             const float* __restrict__ Wc2, const float* __restrict__ bc2,
                             float* __restrict__ out) {
    int lane = threadIdx.x & 63;
    int wslot = threadIdx.x >> 6;
    int s = blockIdx.x * 4 + wslot;
    __shared__ float e_sh[4][256];
    const float* hr = h_last + (size_t)s * 256;
    #pragma unroll
    for (int i = 0; i < 4; i++) {
        float v = hr[lane + 64 * i];
        e_sh[wslot][lane + 64 * i] = fmaxf(v, 0.f);
    }
    __syncthreads();
    float zpart = 0.f;
    #pragma unroll
    for (int jj = 0; jj < 2; jj++) {
        int j = lane + 64 * jj;
        float a = bc1[j];
        const float4* wr = (const float4*)(Wc1 + (size_t)j * 256);
        #pragma unroll 8
        for (int k4 = 0; k4 < 64; k4++) {
            float4 wv = wr[k4];
            float4 e = *(const float4*)&e_sh[wslot][k4 * 4];
            a += wv.x * e.x + wv.y * e.y + wv.z * e.z + wv.w * e.w;
        }
        a = fmaxf(a, 0.f);
        zpart += a * Wc2[j];
    }
    #pragma unroll
    for (int off = 32; off > 0; off >>= 1) zpart += __shfl_down(zpart, off);
    if (lane == 0) out[s] = zpart + bc2[0];
}

// ---------------- launcher ----------------

extern "C" void kernel_launch(void* const* d_in, const int* in_sizes, int n_in,
                              void* d_out, int out_size, void* d_ws, size_t ws_size,
                              hipStream_t stream) {
    const float* inputs = (const float*)d_in[0];
    const float* W1  = (const float*)d_in[1];
    const float* b1  = (const float*)d_in[2];
    const float* W2  = (const float*)d_in[3];
    const float* b2  = (const float*)d_in[4];
    const float* Wi  = (const float*)d_in[5];
    const float* Wh  = (const float*)d_in[6];
    const float* bi  = (const float*)d_in[7];
    const float* bh  = (const float*)d_in[8];
    const float* Wc1 = (const float*)d_in[9];
    const float* bc1 = (const float*)d_in[10];
    const float* Wc2 = (const float*)d_in[11];
    const float* bc2 = (const float*)d_in[12];
    const int* src      = (const int*)d_in[13];
    const int* dst      = (const int*)d_in[14];
    const int* sidx     = (const int*)d_in[15];
    const int* lengths  = (const int*)d_in[16];
    float* out = (float*)d_out;

    char* ws = (char*)d_ws;
    size_t off = 0;
    auto alloc = [&](size_t bytes) -> void* {
        void* p = ws + off;
        off = (off + bytes + 255) & ~(size_t)255;
        return p;
    };
    unsigned short* in_bf  = (unsigned short*)alloc(2 * (size_t)N_NODES * EMB);
    unsigned short* agg_bf = (unsigned short*)alloc(2 * (size_t)N_NODES * EMB);
    unsigned short* h_bf   = (unsigned short*)alloc(2 * (size_t)N_NODES * EMB);
    unsigned short* hn_bf  = (unsigned short*)alloc(2 * (size_t)N_NODES * EMB);
    int*   row_ptr  = (int*)alloc(sizeof(int) * (N_NODES + 1));
    int*   cnt      = (int*)alloc(sizeof(int) * N_NODES);
    int*   blk      = (int*)alloc(sizeof(int) * SCAN_NB);
    int*   edge_src = (int*)alloc(sizeof(int) * N_EDGES);
    unsigned short* Wpk  = (unsigned short*)alloc(2 * 1024 * 384);
    unsigned short* W1b  = (unsigned short*)alloc(2 * 128 * 128);
    unsigned short* W2b  = (unsigned short*)alloc(2 * 128 * 128);
    float* bsum     = (float*)alloc(sizeof(float) * 1024);
    float* hlast    = (float*)alloc(sizeof(float) * NSENT * LH);

    // weight prep (independent of everything else)
    k_prep<<<(1024 * 384 + 1024 + 32768 + 255) / 256, 256, 0, stream>>>(
        Wi, Wh, bi, bh, W1, W2, Wpk, bsum, W1b, W2b);

    // CSR build
    hipMemsetAsync(cnt, 0, sizeof(int) * N_NODES, stream);
    k_hist<<<(N_EDGES + 255) / 256, 256, 0, stream>>>(dst, cnt);
    k_scan_blk<<<SCAN_NB, 256, 0, stream>>>(cnt, row_ptr, blk);
    k_scan_tot<<<1, 256, 0, stream>>>(blk);
    k_scan_add<<<SCAN_NB, 256, 0, stream>>>(row_ptr, blk);
    hipMemsetAsync(cnt, 0, sizeof(int) * N_NODES, stream);
    k_scatter<<<(N_EDGES + 255) / 256, 256, 0, stream>>>(src, dst, row_ptr, cnt, edge_src);

    // GCN (bf16 path)
    k_tobf16<<<(N_NODES * EMB / 4 + 255) / 256, 256, 0, stream>>>(inputs, in_bf);
    k_aggregate_bf<<<(N_NODES * 64) / 256, 256, 0, stream>>>(in_bf, row_ptr, edge_src, agg_bf);
    k_gcn_mfma<<<(N_NODES + 63) / 64, 256, 0, stream>>>(agg_bf, W1b, b1, h_bf, N_NODES, 1);
    k_aggregate_bf<<<(N_NODES * 64) / 256, 256, 0, stream>>>(h_bf, row_ptr, edge_src, agg_bf);
    k_gcn_mfma<<<(N_NODES + 63) / 64, 256, 0, stream>>>(agg_bf, W2b, b2, hn_bf, N_NODES, 0);

    // LSTM: 64 self-contained blocks x 1024 threads, no inter-block sync
    k_lstm_block<<<64, 1024, 0, stream>>>(hn_bf, Wpk, bsum, sidx, lengths, hlast);

    // classifier
    k_classifier<<<NSENT / 4, 256, 0, stream>>>(hlast, Wc1, bc1, Wc2, bc2, out);
}

// Round 9
// 856.805 us; speedup vs baseline: 1.6019x; 1.4821x over previous
//
#include <hip/hip_runtime.h>
#include <hip/hip_bf16.h>
#include <math.h>

#define N_NODES 50000
#define N_EDGES 800000
#define EMB 128
#define LH 256
#define NSENT 2048
#define MAXLEN 32
#define SCAN_NB 196   // ceil(50000/256)

typedef __attribute__((ext_vector_type(8))) short short8;
typedef __attribute__((ext_vector_type(4))) float f32x4;

__device__ __forceinline__ unsigned short f2bf_u(float f) {
    __hip_bfloat16 h = __float2bfloat16(f);
    return *reinterpret_cast<unsigned short*>(&h);
}
__device__ __forceinline__ float bfu2f(unsigned short u) {
    unsigned int x = ((unsigned int)u) << 16;
    return __uint_as_float(x);
}

// ---------------- CSR build ----------------

__global__ void k_hist(const int* __restrict__ dst, int* __restrict__ cnt) {
    int i = blockIdx.x * 256 + threadIdx.x;
    if (i < N_EDGES) atomicAdd(&cnt[dst[i]], 1);
}

__global__ void k_scan_blk(const int* __restrict__ cnt, int* __restrict__ row_ptr,
                           int* __restrict__ blk) {
    int b = blockIdx.x, t = threadIdx.x;
    int i = b * 256 + t;
    int lane = t & 63, wid = t >> 6;
    int v = (i < N_NODES) ? cnt[i] : 0;
    int x = v;
    #pragma unroll
    for (int off = 1; off < 64; off <<= 1) {
        int y = __shfl_up(x, off);
        if (lane >= off) x += y;
    }
    __shared__ int ws[4];
    if (lane == 63) ws[wid] = x;
    __syncthreads();
    if (t == 0) {
        int s = 0;
        #pragma unroll
        for (int j = 0; j < 4; j++) { int tmp = ws[j]; ws[j] = s; s += tmp; }
        blk[b] = s;
    }
    __syncthreads();
    if (i < N_NODES) row_ptr[i] = ws[wid] + x - v;
}

__global__ void k_scan_tot(int* __restrict__ blk) {
    int t = threadIdx.x;
    int lane = t & 63, wid = t >> 6;
    int v = (t < SCAN_NB) ? blk[t] : 0;
    int x = v;
    #pragma unroll
    for (int off = 1; off < 64; off <<= 1) {
        int y = __shfl_up(x, off);
        if (lane >= off) x += y;
    }
    __shared__ int ws[4];
    if (lane == 63) ws[wid] = x;
    __syncthreads();
    if (t == 0) {
        int s = 0;
        #pragma unroll
        for (int j = 0; j < 4; j++) { int tmp = ws[j]; ws[j] = s; s += tmp; }
    }
    __syncthreads();
    if (t < SCAN_NB) blk[t] = ws[wid] + x - v;
}

__global__ void k_scan_add(int* __restrict__ row_ptr, const int* __restrict__ blk) {
    int i = blockIdx.x * 256 + threadIdx.x;
    if (i < N_NODES) row_ptr[i] += blk[i >> 8];
    if (i == 0) row_ptr[N_NODES] = N_EDGES;
}

__global__ void k_scatter(const int* __restrict__ src, const int* __restrict__ dst,
                          const int* __restrict__ row_ptr, int* __restrict__ cnt,
                          int* __restrict__ edge_src) {
    int i = blockIdx.x * 256 + threadIdx.x;
    if (i < N_EDGES) {
        int d = dst[i];
        int pos = row_ptr[d] + atomicAdd(&cnt[d], 1);
        edge_src[pos] = src[i];
    }
}

// ---------------- fp32 -> bf16 convert (inputs) ----------------

__global__ void k_tobf16(const float* __restrict__ x, unsigned short* __restrict__ y) {
    int i = blockIdx.x * 256 + threadIdx.x;
    float4 v = ((const float4*)x)[i];
    ushort4 u;
    u.x = f2bf_u(v.x); u.y = f2bf_u(v.y); u.z = f2bf_u(v.z); u.w = f2bf_u(v.w);
    ((ushort4*)y)[i] = u;
}

// ---------------- aggregation: wave per node, 4 edge-slots x 16B/lane ----------------

__global__ void k_aggregate_bf(const unsigned short* __restrict__ feat,
                               const int* __restrict__ row_ptr,
                               const int* __restrict__ edge_src,
                               unsigned short* __restrict__ outb) {
    int w = (blockIdx.x * 256 + threadIdx.x) >> 6;
    int lane = threadIdx.x & 63;
    if (w >= N_NODES) return;
    int slot = lane >> 4, li = lane & 15;
    int beg = row_ptr[w], end = row_ptr[w + 1];
    float acc[8] = {};
    #pragma unroll 1
    for (int e = beg; e < end; e += 4) {
        int eidx = e + slot;
        if (eidx < end) {
            int s = edge_src[eidx];
            short8 v = *(const short8*)((const short*)feat + (size_t)s * EMB + li * 8);
            #pragma unroll
            for (int j = 0; j < 8; j++) acc[j] += bfu2f((unsigned short)v[j]);
        }
    }
    #pragma unroll
    for (int j = 0; j < 8; j++) {
        float t = acc[j];
        t += __shfl_xor(t, 16);
        t += __shfl_xor(t, 32);
        acc[j] = t;
    }
    if (slot == 0) {
        short8 o;
        #pragma unroll
        for (int j = 0; j < 8; j++) o[j] = (short)f2bf_u(acc[j]);
        *(short8*)((short*)outb + (size_t)w * EMB + li * 8) = o;
    }
}

// ---------------- GCN linear via MFMA ----------------

__global__ void __launch_bounds__(256)
k_gcn_mfma(const unsigned short* __restrict__ Ab,   // [M][128] bf16
           const unsigned short* __restrict__ Wb,   // [128][128] bf16
           const float* __restrict__ bias,
           unsigned short* __restrict__ outb,
           int M, int do_tanh) {
    int tid = threadIdx.x;
    int w = tid >> 6, lane = tid & 63;
    int l16 = lane & 15, quad = lane >> 4;
    int rbase = blockIdx.x * 64 + w * 16;
    int arow = rbase + l16;
    if (arow >= M) arow = M - 1;
    const short* Ap = (const short*)Ab + (size_t)arow * 128 + quad * 8;
    const short* Wp = (const short*)Wb;
    f32x4 acc[8] = {};
    #pragma unroll
    for (int ks = 0; ks < 4; ks++) {
        short8 a = *(const short8*)(Ap + ks * 32);
        #pragma unroll
        for (int ct = 0; ct < 8; ct++) {
            short8 b = *(const short8*)(Wp + (size_t)(ct * 16 + l16) * 128 + ks * 32 + quad * 8);
            acc[ct] = __builtin_amdgcn_mfma_f32_16x16x32_bf16(a, b, acc[ct], 0, 0, 0);
        }
    }
    #pragma unroll
    for (int ct = 0; ct < 8; ct++) {
        float bcol = bias[ct * 16 + l16];
        #pragma unroll
        for (int r = 0; r < 4; r++) {
            int row = rbase + quad * 4 + r;
            if (row < M) {
                float v = acc[ct][r] + bcol;
                if (do_tanh) v = tanhf(v);
                outb[(size_t)row * 128 + ct * 16 + l16] = f2bf_u(v);
            }
        }
    }
}

// ---------------- prep: Wpk (fragment-linear packed LSTM weights), bsum, W1b, W2b ----------------
// Wpk: fragment (ct,ks) at ((ct*12+ks)<<9) shorts; element lane*8+jj =
//   W[ct*16 + (lane&15)][ks*32 + (lane>>4)*8 + jj]  -> 1KB coalesced per wave-load.

__global__ void k_prep(const float* __restrict__ Wi, const float* __restrict__ Wh,
                       const float* __restrict__ bi, const float* __restrict__ bh,
                       const float* __restrict__ W1, const float* __restrict__ W2,
                       unsigned short* __restrict__ Wpk, float* __restrict__ bsum,
                       unsigned short* __restrict__ W1b, unsigned short* __restrict__ W2b) {
    int idx = blockIdx.x * 256 + threadIdx.x;
    if (idx < 1024 * 384) {
        int R = idx / 384, k = idx - R * 384;
        float v = (k < 128) ? Wi[R * 128 + k] : Wh[R * 256 + (k - 128)];
        int ct = R >> 4, cin = R & 15;
        int ks = k >> 5, kk = k & 31;
        int q = kk >> 3, jj = kk & 7;
        Wpk[((ct * 12 + ks) << 9) + (q * 16 + cin) * 8 + jj] = f2bf_u(v);
    } else if (idx < 1024 * 384 + 1024) {
        int r = idx - 1024 * 384;
        bsum[r] = bi[r] + bh[r];
    } else if (idx < 1024 * 384 + 1024 + 16384) {
        int r = idx - (1024 * 384 + 1024);
        W1b[r] = f2bf_u(W1[r]);
    } else if (idx < 1024 * 384 + 1024 + 32768) {
        int r = idx - (1024 * 384 + 1024 + 16384);
        W2b[r] = f2bf_u(W2[r]);
    }
}

// ---------------- LSTM: 64 self-contained blocks x 1024 threads (16 waves) ----------------
// R4's PROVEN weight path (inline just-in-time b-loads, consumed immediately by MFMA —
// NO staging arrays; R5-R8 evidence: any explicit ping-pong buffer structure triggers
// ~750 MB deterministic HBM traffic on this toolchain) scaled to 16 waves (4 waves/EU ->
// 2x outstanding loads vs R4's 2 waves/EU, same load->use structure). Wave w owns units
// [w*16,w*16+16), all 4 gates (ct = g*16 + w). acc 32 VGPR + transients => R4 regime.
// h in LDS double-buffer, XOR-swizzled (chunk ^ (m&7)); c in registers.

__global__ void __launch_bounds__(1024)
k_lstm_block(const unsigned short* __restrict__ hn_bf,   // [N_NODES][128] bf16
             const unsigned short* __restrict__ Wpk,     // packed, see k_prep
             const float* __restrict__ bsum,             // [1024]
             const int* __restrict__ sidx,               // [NSENT][MAXLEN]
             const int* __restrict__ lengths,            // [NSENT]
             float* __restrict__ h_last) {               // [NSENT][256] fp32
    __shared__ unsigned short hsh[2][32 * 256];          // 32 KB
    __shared__ int nid_sh[32 * 33];                      // [m][t], pitch 33
    __shared__ int len_sh[32];
    int tid = threadIdx.x;
    int w = tid >> 6, lane = tid & 63;                   // w in [0,16)
    int l16 = lane & 15, quad = lane >> 4;
    int s0 = blockIdx.x * 32;

    for (int i = tid; i < 32 * 32; i += 1024)
        nid_sh[(i >> 5) * 33 + (i & 31)] = sidx[(size_t)(s0 + (i >> 5)) * MAXLEN + (i & 31)];
    if (tid < 32) len_sh[tid] = lengths[s0 + tid];
    for (int i = tid; i < 32 * 256; i += 1024) hsh[0][i] = 0;   // h_{-1} = 0
    __syncthreads();

    const short* hnp = (const short*)hn_bf;
    const short* Wp = (const short*)Wpk;

    float bs[4];
    #pragma unroll
    for (int g = 0; g < 4; g++) bs[g] = bsum[g * 256 + w * 16 + l16];

    float c_reg[2][4] = {};   // [mt][r]
    int u = w * 16 + l16;
    int swz = (l16 & 7) * 8;  // XOR term (shorts) for h LDS chunk swizzle

    #pragma unroll 1
    for (int t = 0; t < MAXLEN; t++) {
        const short* hin = (const short*)hsh[t & 1];
        unsigned short* hout = hsh[(t & 1) ^ 1];

        int nid0 = nid_sh[l16 * 33 + t];
        int nid1 = nid_sh[(16 + l16) * 33 + t];
        const short* Ax0 = hnp + (size_t)nid0 * 128 + quad * 8;
        const short* Ax1 = hnp + (size_t)nid1 * 128 + quad * 8;

        f32x4 acc0[4] = {};   // m-tile 0 (m = quad*4+r), per gate
        f32x4 acc1[4] = {};   // m-tile 1 (m = 16+quad*4+r)

        // X phase: gates += x_t @ Wi.T (ks 0..3); inline b-loads, R4 style
        #pragma unroll 2
        for (int ks = 0; ks < 4; ks++) {
            short8 a0 = *(const short8*)(Ax0 + ks * 32);
            short8 a1 = *(const short8*)(Ax1 + ks * 32);
            #pragma unroll
            for (int g = 0; g < 4; g++) {
                short8 b = *(const short8*)(Wp + (((g * 16 + w) * 12 + ks) << 9) + lane * 8);
                acc0[g] = __builtin_amdgcn_mfma_f32_16x16x32_bf16(a0, b, acc0[g], 0, 0, 0);
                acc1[g] = __builtin_amdgcn_mfma_f32_16x16x32_bf16(a1, b, acc1[g], 0, 0, 0);
            }
        }
        // H phase: gates += h_{t-1} @ Wh.T (ks 4..11, A from swizzled LDS)
        if (t > 0) {
            #pragma unroll 2
            for (int ks = 4; ks < 12; ks++) {
                int go = ((ks - 4) * 4 + quad) * 8;
                short8 a0 = *(const short8*)(hin + l16 * 256 + (go ^ swz));
                short8 a1 = *(const short8*)(hin + (16 + l16) * 256 + (go ^ swz));
                #pragma unroll
                for (int g = 0; g < 4; g++) {
                    short8 b = *(const short8*)(Wp + (((g * 16 + w) * 12 + ks) << 9) + lane * 8);
                    acc0[g] = __builtin_amdgcn_mfma_f32_16x16x32_bf16(a0, b, acc0[g], 0, 0, 0);
                    acc1[g] = __builtin_amdgcn_mfma_f32_16x16x32_bf16(a1, b, acc1[g], 0, 0, 0);
                }
            }
        }

        // epilogue: per-lane pointwise update; c in registers; h -> LDS (swizzled)
        #pragma unroll
        for (int mt = 0; mt < 2; mt++)
            #pragma unroll
            for (int r = 0; r < 4; r++) {
                int m = mt * 16 + quad * 4 + r;
                float gi  = (mt ? acc1[0][r] : acc0[0][r]) + bs[0];
                float gf  = (mt ? acc1[1][r] : acc0[1][r]) + bs[1];
                float gg  = (mt ? acc1[2][r] : acc0[2][r]) + bs[2];
                float go_ = (mt ? acc1[3][r] : acc0[3][r]) + bs[3];
                float i_ = 1.f / (1.f + expf(-gi));
                float f_ = 1.f / (1.f + expf(-gf));
                float g_ = tanhf(gg);
                float o_ = 1.f / (1.f + expf(-go_));
                float c = f_ * c_reg[mt][r] + i_ * g_;
                c_reg[mt][r] = c;
                float h = o_ * tanhf(c);
                hout[m * 256 + ((((u >> 3) ^ (m & 7)) << 3) | (u & 7))] = f2bf_u(h);
                if (len_sh[m] - 1 == t) h_last[(size_t)(s0 + m) * 256 + u] = h;
            }
        __syncthreads();
    }
}

// ---------------- classifier ----------------

__global__ void k_classifier(const float* __restrict__ h_last,
                             const float* __restrict__ Wc1, const float* __restrict__ bc1,
                             const float* __restrict__ Wc2, const float* __restrict__ bc2,
                             float* __restrict__ out) {
    int lane = threadIdx.x & 63;
    int wslot = threadIdx.x >> 6;
    int s = blockIdx.x * 4 + wslot;
    __shared__ float e_sh[4][256];
    const float* hr = h_last + (size_t)s * 256;
    #pragma unroll
    for (int i = 0; i < 4; i++) {
        float v = hr[lane + 64 * i];
        e_sh[wslot][lane + 64 * i] = fmaxf(v, 0.f);
    }
    __syncthreads();
    float zpart = 0.f;
    #pragma unroll
    for (int jj = 0; jj < 2; jj++) {
        int j = lane + 64 * jj;
        float a = bc1[j];
        const float4* wr = (const float4*)(Wc1 + (size_t)j * 256);
        #pragma unroll 8
        for (int k4 = 0; k4 < 64; k4++) {
            float4 wv = wr[k4];
            float4 e = *(const float4*)&e_sh[wslot][k4 * 4];
            a += wv.x * e.x + wv.y * e.y + wv.z * e.z + wv.w * e.w;
        }
        a = fmaxf(a, 0.f);
        zpart += a * Wc2[j];
    }
    #pragma unroll
    for (int off = 32; off > 0; off >>= 1) zpart += __shfl_down(zpart, off);
    if (lane == 0) out[s] = zpart + bc2[0];
}

// ---------------- launcher ----------------

extern "C" void kernel_launch(void* const* d_in, const int* in_sizes, int n_in,
                              void* d_out, int out_size, void* d_ws, size_t ws_size,
                              hipStream_t stream) {
    const float* inputs = (const float*)d_in[0];
    const float* W1  = (const float*)d_in[1];
    const float* b1  = (const float*)d_in[2];
    const float* W2  = (const float*)d_in[3];
    const float* b2  = (const float*)d_in[4];
    const float* Wi  = (const float*)d_in[5];
    const float* Wh  = (const float*)d_in[6];
    const float* bi  = (const float*)d_in[7];
    const float* bh  = (const float*)d_in[8];
    const float* Wc1 = (const float*)d_in[9];
    const float* bc1 = (const float*)d_in[10];
    const float* Wc2 = (const float*)d_in[11];
    const float* bc2 = (const float*)d_in[12];
    const int* src      = (const int*)d_in[13];
    const int* dst      = (const int*)d_in[14];
    const int* sidx     = (const int*)d_in[15];
    const int* lengths  = (const int*)d_in[16];
    float* out = (float*)d_out;

    char* ws = (char*)d_ws;
    size_t off = 0;
    auto alloc = [&](size_t bytes) -> void* {
        void* p = ws + off;
        off = (off + bytes + 255) & ~(size_t)255;
        return p;
    };
    unsigned short* in_bf  = (unsigned short*)alloc(2 * (size_t)N_NODES * EMB);
    unsigned short* agg_bf = (unsigned short*)alloc(2 * (size_t)N_NODES * EMB);
    unsigned short* h_bf   = (unsigned short*)alloc(2 * (size_t)N_NODES * EMB);
    unsigned short* hn_bf  = (unsigned short*)alloc(2 * (size_t)N_NODES * EMB);
    int*   row_ptr  = (int*)alloc(sizeof(int) * (N_NODES + 1));
    int*   cnt      = (int*)alloc(sizeof(int) * N_NODES);
    int*   blk      = (int*)alloc(sizeof(int) * SCAN_NB);
    int*   edge_src = (int*)alloc(sizeof(int) * N_EDGES);
    unsigned short* Wpk  = (unsigned short*)alloc(2 * 1024 * 384);
    unsigned short* W1b  = (unsigned short*)alloc(2 * 128 * 128);
    unsigned short* W2b  = (unsigned short*)alloc(2 * 128 * 128);
    float* bsum     = (float*)alloc(sizeof(float) * 1024);
    float* hlast    = (float*)alloc(sizeof(float) * NSENT * LH);

    // weight prep (independent of everything else)
    k_prep<<<(1024 * 384 + 1024 + 32768 + 255) / 256, 256, 0, stream>>>(
        Wi, Wh, bi, bh, W1, W2, Wpk, bsum, W1b, W2b);

    // CSR build
    hipMemsetAsync(cnt, 0, sizeof(int) * N_NODES, stream);
    k_hist<<<(N_EDGES + 255) / 256, 256, 0, stream>>>(dst, cnt);
    k_scan_blk<<<SCAN_NB, 256, 0, stream>>>(cnt, row_ptr, blk);
    k_scan_tot<<<1, 256, 0, stream>>>(blk);
    k_scan_add<<<SCAN_NB, 256, 0, stream>>>(row_ptr, blk);
    hipMemsetAsync(cnt, 0, sizeof(int) * N_NODES, stream);
    k_scatter<<<(N_EDGES + 255) / 256, 256, 0, stream>>>(src, dst, row_ptr, cnt, edge_src);

    // GCN (bf16 path)
    k_tobf16<<<(N_NODES * EMB / 4 + 255) / 256, 256, 0, stream>>>(inputs, in_bf);
    k_aggregate_bf<<<(N_NODES * 64) / 256, 256, 0, stream>>>(in_bf, row_ptr, edge_src, agg_bf);
    k_gcn_mfma<<<(N_NODES + 63) / 64, 256, 0, stream>>>(agg_bf, W1b, b1, h_bf, N_NODES, 1);
    k_aggregate_bf<<<(N_NODES * 64) / 256, 256, 0, stream>>>(h_bf, row_ptr, edge_src, agg_bf);
    k_gcn_mfma<<<(N_NODES + 63) / 64, 256, 0, stream>>>(agg_bf, W2b, b2, hn_bf, N_NODES, 0);

    // LSTM: 64 self-contained blocks x 1024 threads, inline weight loads (R4 path)
    k_lstm_block<<<64, 1024, 0, stream>>>(hn_bf, Wpk, bsum, sidx, lengths, hlast);

    // classifier
    k_classifier<<<NSENT / 4, 256, 0, stream>>>(hlast, Wc1, bc1, Wc2, bc2, out);
}